// Round 13
// baseline (464.561 us; speedup 1.0000x reference)
//
#include <hip/hip_runtime.h>
#include <stdint.h>

#define NCLASS 41
#define TLEN   1024
#define NBATCH 1024
// per-batch backpointer stride: (TLEN-1)*NCLASS = 41943, round to mult of 8
#define BP_STRIDE 41944
#define NTRANS (NCLASS * NCLASS)
#define NEGINF (-3.0e38f)
#define EPS    2.0e-3f
#define MASK41 ((1ull << NCLASS) - 1)

#define RDLANE(v, l) __int_as_float(__builtin_amdgcn_readlane(__float_as_int(v), (l)))

// Full-wave max + broadcast via DPP (row_shr 1/2/4/8, row_bcast 15/31).
__device__ __forceinline__ float wave_max_bcast(float x) {
    int xi = __float_as_int(x);
    int t;
    t = __builtin_amdgcn_update_dpp(xi, xi, 0x111, 0xf, 0xf, false);  // row_shr:1
    x = fmaxf(x, __int_as_float(t)); xi = __float_as_int(x);
    t = __builtin_amdgcn_update_dpp(xi, xi, 0x112, 0xf, 0xf, false);  // row_shr:2
    x = fmaxf(x, __int_as_float(t)); xi = __float_as_int(x);
    t = __builtin_amdgcn_update_dpp(xi, xi, 0x114, 0xf, 0xf, false);  // row_shr:4
    x = fmaxf(x, __int_as_float(t)); xi = __float_as_int(x);
    t = __builtin_amdgcn_update_dpp(xi, xi, 0x118, 0xf, 0xf, false);  // row_shr:8
    x = fmaxf(x, __int_as_float(t)); xi = __float_as_int(x);
    t = __builtin_amdgcn_update_dpp(xi, xi, 0x142, 0xf, 0xf, false);  // row_bcast:15
    x = fmaxf(x, __int_as_float(t)); xi = __float_as_int(x);
    t = __builtin_amdgcn_update_dpp(xi, xi, 0x143, 0xf, 0xf, false);  // row_bcast:31
    x = fmaxf(x, __int_as_float(t));
    return __int_as_float(__builtin_amdgcn_readlane(__float_as_int(x), 63));
}

// ---------------------------------------------------------------------------
// Viterbi forward = round-11 peel + round-7 lagged threshold (one-variable
// experiment vs r11; both halves individually HW-verified bit-exact).
//
// thr_{t+1} = M_{t-1} + E_t + (Dmin - D - EPS) <= M_t - D - eps'
//   (winner i of any column j satisfies s[i] >= M - D; M_t >= M_{t-1}+E_t+Dmin)
// => ballot superset is exact-safe; candidates processed ascending with
// strict >, preserving first-index argmax. M_{t-1} = tree(pre-update score)
// runs DURING step t (off-chain); E_t = tree(emission row t) runs 4 steps
// early at prefetch (rolling E0..E3). Chain per step: add -> ballot ->
// ffs/clz -> readlane x2 -> ds x2 -> add x2 -> merge -> store. Window is
// [D,2D]: 4-wide branch (~30%), serial only cnt>=5 (~3%).
// ---------------------------------------------------------------------------
__global__ __launch_bounds__(64, 1) void crf_forward(
    const float* __restrict__ x,        // [B, T, C]
    const float* __restrict__ start_t,  // [C]
    const float* __restrict__ end_t,    // [C]
    const float* __restrict__ trans,    // [C, C]
    uint8_t* __restrict__ bp,           // [B, BP_STRIDE]
    int* __restrict__ out)              // [B, T]
{
    __shared__ float tl[NTRANS + 32];   // trans rows; pad so reads never OOB

    const int b = blockIdx.x;
    const int j = threadIdx.x;
    const int jc = (j < NCLASS) ? j : (NCLASS - 1);  // mirror lanes 41..63

    // Stage trans into LDS; D = max - min (exact, from data)
    float mx = NEGINF, mn = 3.0e38f;
    for (int k = j; k < NTRANS; k += 64) {
        float v = trans[k];
        tl[k] = v;
        mx = fmaxf(mx, v);
        mn = fminf(mn, v);
    }
    __syncthreads();
    const float Dmax = wave_max_bcast(mx);
    const float Dmin = -wave_max_bcast(-mn);
    const float D  = Dmax - Dmin;
    const float Cc = Dmin - D - EPS;    // lagged-threshold constant (r7)

    const float* xb = x + (size_t)b * TLEN * NCLASS;
    uint8_t* bpb = bp + (size_t)b * BP_STRIDE;

    // All lanes live: lanes 41-63 mirror lane 40 (same loads, same values).
    float score = start_t[jc] + xb[jc];

    // Bootstrap: exact (zero-lag) threshold for step 1 (r7, verified).
    float thr = wave_max_bcast(score) - D - EPS;

    // One step. e/E = this step's emission and its wave-max (prefetched).
    auto step = [&](float e, float E, int boff) {
        unsigned long long me = __ballot(score >= thr) & MASK41;
        int i1 = __ffsll(me) - 1;
        int i2 = 63 - __clzll(me);                    // == i1 when cnt == 1
        unsigned long long mr = me & ~((1ull << i1) | (1ull << i2));
        float s1 = RDLANE(score, i1);
        float s2 = RDLANE(score, i2);
        float t1 = tl[i1 * NCLASS + jc];
        float t2 = tl[i2 * NCLASS + jc];
        // Off-chain: next threshold from PRE-UPDATE score (lag-1 bound).
        float thrN = wave_max_bcast(score) + E + Cc;
        float u1 = s1 + t1;
        float u2 = s2 + t2;
        bool c = u2 > u1;                             // i1 < i2: strict > keeps
        float best = c ? u2 : u1;                     //   first-index semantics
        int bidx = c ? i2 : i1;
        if (__builtin_expect(mr != 0, 0)) {           // cnt >= 3
            int i3 = __ffsll(mr) - 1;
            int i4 = 63 - __clzll(mr);                // == i3 when cnt == 3
            unsigned long long mr2 = mr & ~((1ull << i3) | (1ull << i4));
            float s3 = RDLANE(score, i3);
            float s4 = RDLANE(score, i4);
            float u3 = s3 + tl[i3 * NCLASS + jc];
            float u4 = s4 + tl[i4 * NCLASS + jc];
            // ascending merge order: i1 < i3 <= i4 < i2
            best = u1; bidx = i1;
            if (u3 > best) { best = u3; bidx = i3; }
            if (u4 > best) { best = u4; bidx = i4; }
            if (u2 > best) { best = u2; bidx = i2; }
            if (__builtin_expect(mr2 != 0, 0)) {      // cnt >= 5: exact serial
                best = NEGINF; bidx = 0;
                unsigned long long mm = me;
                while (mm) {
                    int ic = __ffsll(mm) - 1; mm &= mm - 1;
                    float sc = RDLANE(score, ic);
                    float vc = sc + tl[ic * NCLASS + jc];
                    if (vc > best) { best = vc; bidx = ic; }
                }
            }
        }
        bpb[boff] = (uint8_t)bidx;                    // all lanes; mirrors dup
        score = best + e;
        thr = thrN;
    };

    // Rolling 4-deep emission prefetch + per-row wave-max (E), 32-bit offsets.
    int eoff = 1 * NCLASS + jc;          // element offset of em row 1
    float e0 = xb[eoff];
    float e1 = xb[eoff + NCLASS];
    float e2 = xb[eoff + 2 * NCLASS];
    float e3 = xb[eoff + 3 * NCLASS];
    float E0 = wave_max_bcast(e0);
    float E1 = wave_max_bcast(e1);
    float E2 = wave_max_bcast(e2);
    float E3 = wave_max_bcast(e3);
    eoff += 4 * NCLASS;                  // -> row t0+4 while t0 is current
    int boff = jc;                       // bp offset for t = 1

    // Main loop: steps 1..1016 (reloads rows t0+4..t0+7 <= 1020: never OOB)
    int t0 = 1;
    for (; t0 + 7 <= TLEN - 4; t0 += 4) {
        step(e0, E0, boff);              e0 = xb[eoff];              E0 = wave_max_bcast(e0);
        step(e1, E1, boff + NCLASS);     e1 = xb[eoff + NCLASS];     E1 = wave_max_bcast(e1);
        step(e2, E2, boff + 2 * NCLASS); e2 = xb[eoff + 2 * NCLASS]; E2 = wave_max_bcast(e2);
        step(e3, E3, boff + 3 * NCLASS); e3 = xb[eoff + 3 * NCLASS]; E3 = wave_max_bcast(e3);
        eoff += 4 * NCLASS;
        boff += 4 * NCLASS;
    }
    // Tail: t0 == 1017; e0..e3 hold rows 1017..1020. Steps 1017..1020 with
    // reloads of rows 1021..1023 (no OOB), then steps 1021..1023.
    step(e0, E0, boff);              e0 = xb[eoff];              E0 = wave_max_bcast(e0);  // row 1021
    step(e1, E1, boff + NCLASS);     e1 = xb[eoff + NCLASS];     E1 = wave_max_bcast(e1);  // row 1022
    step(e2, E2, boff + 2 * NCLASS); e2 = xb[eoff + 2 * NCLASS]; E2 = wave_max_bcast(e2);  // row 1023
    step(e3, E3, boff + 3 * NCLASS);
    boff += 4 * NCLASS;
    step(e0, E0, boff);
    step(e1, E1, boff + NCLASS);
    step(e2, E2, boff + 2 * NCLASS);

    // Final: add end transitions, argmax over lanes (first-index on tie).
    // Mirror lanes tie with lane 40; lower index wins, so result < 41.
    float fs = score + end_t[jc];
    int idx = j;
#pragma unroll
    for (int off = 32; off >= 1; off >>= 1) {
        float ov = __shfl_xor(fs, off);
        int oi = __shfl_xor(idx, off);
        if (ov > fs || (ov == fs && oi < idx)) { fs = ov; idx = oi; }
    }
    if (j == 0) out[(size_t)b * TLEN + (TLEN - 1)] = idx;
}

// ---------------------------------------------------------------------------
// Kernel B: backtracking (unchanged; measured cheap ~3us).
// ---------------------------------------------------------------------------
__global__ __launch_bounds__(1024) void crf_backtrack(
    const uint8_t* __restrict__ bp,
    int* __restrict__ out)
{
    __shared__ uint8_t bpl[BP_STRIDE];     // 41944 B
    __shared__ int maps[16][NCLASS];       // chunk boundary maps
    __shared__ int entry[16];              // true tag at each chunk end

    const int b = blockIdx.x;
    const int tid = threadIdx.x;
    const int w = tid >> 6;
    const int lane = tid & 63;

    {
        const uint32_t* src = (const uint32_t*)(bp + (size_t)b * BP_STRIDE);
        uint32_t* dst = (uint32_t*)bpl;
        for (int i = tid; i < BP_STRIDE / 4; i += 1024) dst[i] = src[i];
    }
    __syncthreads();

    const int cs = w * 64;
    const int ce = min(cs + 64, TLEN - 1);  // last chunk: 63 columns
    const int L = ce - cs;

    // Phase 1: hypothesis walk for all 41 entering tags (lane = hypothesis)
    {
        int xx = (lane < NCLASS) ? lane : 0;
        for (int t = ce; t > cs; --t)
            xx = bpl[(t - 1) * NCLASS + xx];
        if (lane < NCLASS) maps[w][lane] = xx;
    }
    __syncthreads();

    // Stitch chunk boundaries serially on one thread
    if (tid == 0) {
        int cur = out[(size_t)b * TLEN + (TLEN - 1)];  // tag @ T-1 from fwd
        for (int ww = 15; ww >= 0; --ww) {
            entry[ww] = cur;
            cur = maps[ww][cur];
        }
    }
    __syncthreads();

    // Phase 2: replay with true entering tag; lane l captures step l's tag
    {
        int xx = entry[w];
        int cap = 0;
        for (int k = 0; k < L; ++k) {
            xx = bpl[(ce - 1 - k) * NCLASS + xx];
            if (k == lane) cap = xx;
        }
        if (lane < L) out[(size_t)b * TLEN + (ce - 1 - lane)] = cap;
    }
}

// ---------------------------------------------------------------------------
extern "C" void kernel_launch(void* const* d_in, const int* in_sizes, int n_in,
                              void* d_out, int out_size, void* d_ws, size_t ws_size,
                              hipStream_t stream) {
    const float* x       = (const float*)d_in[0];
    const float* start_t = (const float*)d_in[1];
    const float* end_t   = (const float*)d_in[2];
    const float* trans   = (const float*)d_in[3];
    int* out = (int*)d_out;
    uint8_t* bp = (uint8_t*)d_ws;  // needs NBATCH * BP_STRIDE = ~42.9 MB

    crf_forward<<<NBATCH, 64, 0, stream>>>(x, start_t, end_t, trans, bp, out);
    crf_backtrack<<<NBATCH, 1024, 0, stream>>>(bp, out);
}

// Round 14
// 257.905 us; speedup vs baseline: 1.8013x; 1.8013x over previous
//
#include <hip/hip_runtime.h>
#include <stdint.h>

#define NCLASS 41
#define TLEN   1024
#define NBATCH 1024
// per-batch backpointer stride: (TLEN-1)*NCLASS = 41943, round to mult of 8
#define BP_STRIDE 41944
#define NTRANS (NCLASS * NCLASS)
#define NEGINF (-3.0e38f)
#define EPS    2.0e-3f
#define MASK41 ((1ull << NCLASS) - 1)

#define RDLANE(v, l) __int_as_float(__builtin_amdgcn_readlane(__float_as_int(v), (l)))

// Full-wave max + broadcast via DPP (row_shr 1/2/4/8, row_bcast 15/31).
__device__ __forceinline__ float wave_max_bcast(float x) {
    int xi = __float_as_int(x);
    int t;
    t = __builtin_amdgcn_update_dpp(xi, xi, 0x111, 0xf, 0xf, false);  // row_shr:1
    x = fmaxf(x, __int_as_float(t)); xi = __float_as_int(x);
    t = __builtin_amdgcn_update_dpp(xi, xi, 0x112, 0xf, 0xf, false);  // row_shr:2
    x = fmaxf(x, __int_as_float(t)); xi = __float_as_int(x);
    t = __builtin_amdgcn_update_dpp(xi, xi, 0x114, 0xf, 0xf, false);  // row_shr:4
    x = fmaxf(x, __int_as_float(t)); xi = __float_as_int(x);
    t = __builtin_amdgcn_update_dpp(xi, xi, 0x118, 0xf, 0xf, false);  // row_shr:8
    x = fmaxf(x, __int_as_float(t)); xi = __float_as_int(x);
    t = __builtin_amdgcn_update_dpp(xi, xi, 0x142, 0xf, 0xf, false);  // row_bcast:15
    x = fmaxf(x, __int_as_float(t)); xi = __float_as_int(x);
    t = __builtin_amdgcn_update_dpp(xi, xi, 0x143, 0xf, 0xf, false);  // row_bcast:31
    x = fmaxf(x, __int_as_float(t));
    return __int_as_float(__builtin_amdgcn_readlane(__float_as_int(x), 63));
}

// Lane index of the emission-row argmax (any argmax lane works; ffs gives
// the lowest, always < 41 since mirror lanes duplicate lane 40's value).
// Score-independent -> runs entirely off the recurrence chain.
__device__ __forceinline__ int emax_lane(float e) {
    float E = wave_max_bcast(e);
    return __ffsll(__ballot(e >= E)) - 1;
}

// ---------------------------------------------------------------------------
// Viterbi forward. Threshold anchored at the EMISSION-ARGMAX lane:
//   thr_t = score_t[j_e(t)] - D - EPS,   j_e(t) = argmax_j e_t[j].
// Soundness: score_t[j_e] <= M_t, and any column winner w satisfies
// score_t[w] >= M_t - D - 2ulp  =>  thr is a valid lower bound (EPS=2e-3
// >> 2ulp at |score|~2200). Window: score_t[j_e] >= M_t - D (best_j spread
// <= D), so width <= 2D + EPS. One v_readlane replaces the on-chain
// 12-dep-VALU DPP max tree (r11's largest chain block). j_e comes from a
// score-independent tree computed 1 slot after the emission's load lands
// (3 slots of vmcnt slack - the r13 lesson). Peel: r11's exact ascending
// 2-wide + 4-wide branch (cnt>=3) + serial (cnt>=5).
// ---------------------------------------------------------------------------
__global__ __launch_bounds__(64, 1) void crf_forward(
    const float* __restrict__ x,        // [B, T, C]
    const float* __restrict__ start_t,  // [C]
    const float* __restrict__ end_t,    // [C]
    const float* __restrict__ trans,    // [C, C]
    uint8_t* __restrict__ bp,           // [B, BP_STRIDE]
    int* __restrict__ out)              // [B, T]
{
    __shared__ float tl[NTRANS + 32];   // trans rows; pad so reads never OOB

    const int b = blockIdx.x;
    const int j = threadIdx.x;
    const int jc = (j < NCLASS) ? j : (NCLASS - 1);  // mirror lanes 41..63

    // Stage trans into LDS; D = max - min (exact, from data)
    float mx = NEGINF, mn = 3.0e38f;
    for (int k = j; k < NTRANS; k += 64) {
        float v = trans[k];
        tl[k] = v;
        mx = fmaxf(mx, v);
        mn = fminf(mn, v);
    }
    __syncthreads();
    const float Dmax = wave_max_bcast(mx);
    const float Dmin = -wave_max_bcast(-mn);
    const float DpE = (Dmax - Dmin) + EPS;   // D + EPS

    const float* xb = x + (size_t)b * TLEN * NCLASS;
    uint8_t* bpb = bp + (size_t)b * BP_STRIDE;

    // All lanes live: lanes 41-63 mirror lane 40 (same loads, same values).
    float score = start_t[jc] + xb[jc];

    // Bootstrap: exact zero-lag threshold for step 1 (one-time tree).
    float thr = wave_max_bcast(score) - DpE;

    // One step. e = this step's emission; je = argmax lane of e (precomputed,
    // score-independent); boff = bp offset. Sets thr for the NEXT step via a
    // single readlane of the freshly-updated score at lane je.
    auto step = [&](float e, int je, int boff) {
        unsigned long long me = __ballot(score >= thr) & MASK41;
        int i1 = __ffsll(me) - 1;
        int i2 = 63 - __clzll(me);                    // == i1 when cnt == 1
        unsigned long long mr = me & ~((1ull << i1) | (1ull << i2));
        float s1 = RDLANE(score, i1);
        float s2 = RDLANE(score, i2);
        float t1 = tl[i1 * NCLASS + jc];
        float t2 = tl[i2 * NCLASS + jc];
        float u1 = s1 + t1;
        float u2 = s2 + t2;
        bool c = u2 > u1;                             // i1 < i2: strict > keeps
        float best = c ? u2 : u1;                     //   first-index semantics
        int bidx = c ? i2 : i1;
        if (__builtin_expect(mr != 0, 0)) {           // cnt >= 3
            int i3 = __ffsll(mr) - 1;
            int i4 = 63 - __clzll(mr);                // == i3 when cnt == 3
            unsigned long long mr2 = mr & ~((1ull << i3) | (1ull << i4));
            float s3 = RDLANE(score, i3);
            float s4 = RDLANE(score, i4);
            float u3 = s3 + tl[i3 * NCLASS + jc];
            float u4 = s4 + tl[i4 * NCLASS + jc];
            // ascending merge order: i1 < i3 <= i4 < i2
            best = u1; bidx = i1;
            if (u3 > best) { best = u3; bidx = i3; }
            if (u4 > best) { best = u4; bidx = i4; }
            if (u2 > best) { best = u2; bidx = i2; }
            if (__builtin_expect(mr2 != 0, 0)) {      // cnt >= 5: exact serial
                best = NEGINF; bidx = 0;
                unsigned long long mm = me;
                while (mm) {
                    int ic = __ffsll(mm) - 1; mm &= mm - 1;
                    float sc = RDLANE(score, ic);
                    float vc = sc + tl[ic * NCLASS + jc];
                    if (vc > best) { best = vc; bidx = ic; }
                }
            }
        }
        bpb[boff] = (uint8_t)bidx;                    // all lanes; mirrors dup
        score = best + e;
        thr = RDLANE(score, je) - DpE;                // ONE readlane, no tree
    };

    // Rolling 4-deep emission prefetch, 32-bit offsets (SGPR base + voffset).
    int eoff = 1 * NCLASS + jc;          // element offset of em row 1
    float e0 = xb[eoff];
    float e1 = xb[eoff + NCLASS];
    float e2 = xb[eoff + 2 * NCLASS];
    float e3 = xb[eoff + 3 * NCLASS];
    eoff += 4 * NCLASS;                  // -> row t0+4 while t0 is current
    int boff = jc;                       // bp offset for t = 1

    // je pipeline: only je0 needed up front (one-time vmcnt wait);
    // je1..je3 are produced inside the first iteration's slots, each from
    // an emission loaded >= 3 slots earlier (no prefetch stall - r13 lesson).
    int je0 = emax_lane(e0), je1, je2, je3;

    // Main loop: steps 1..1016 (reloads rows t0+4..t0+7 <= 1020: never OOB)
    int t0 = 1;
    for (; t0 + 7 <= TLEN - 4; t0 += 4) {
        step(e0, je0, boff);              e0 = xb[eoff];              je1 = emax_lane(e1);
        step(e1, je1, boff + NCLASS);     e1 = xb[eoff + NCLASS];     je2 = emax_lane(e2);
        step(e2, je2, boff + 2 * NCLASS); e2 = xb[eoff + 2 * NCLASS]; je3 = emax_lane(e3);
        step(e3, je3, boff + 3 * NCLASS); e3 = xb[eoff + 3 * NCLASS]; je0 = emax_lane(e0);
        eoff += 4 * NCLASS;
        boff += 4 * NCLASS;
    }
    // Tail: t0 == 1017; e0..e3 hold rows 1017..1020; je0 ready.
    // Steps 1017..1020 with reloads of rows 1021..1023, then 1021..1023.
    step(e0, je0, boff);              e0 = xb[eoff];              je1 = emax_lane(e1);  // row 1021
    step(e1, je1, boff + NCLASS);     e1 = xb[eoff + NCLASS];     je2 = emax_lane(e2);  // row 1022
    step(e2, je2, boff + 2 * NCLASS); e2 = xb[eoff + 2 * NCLASS]; je3 = emax_lane(e3);  // row 1023
    step(e3, je3, boff + 3 * NCLASS);                             je0 = emax_lane(e0);
    boff += 4 * NCLASS;
    step(e0, je0, boff);                                          je1 = emax_lane(e1);
    step(e1, je1, boff + NCLASS);                                 je2 = emax_lane(e2);
    step(e2, je2, boff + 2 * NCLASS);

    // Final: add end transitions, argmax over lanes (first-index on tie).
    // Mirror lanes tie with lane 40; lower index wins, so result < 41.
    float fs = score + end_t[jc];
    int idx = j;
#pragma unroll
    for (int off = 32; off >= 1; off >>= 1) {
        float ov = __shfl_xor(fs, off);
        int oi = __shfl_xor(idx, off);
        if (ov > fs || (ov == fs && oi < idx)) { fs = ov; idx = oi; }
    }
    if (j == 0) out[(size_t)b * TLEN + (TLEN - 1)] = idx;
}

// ---------------------------------------------------------------------------
// Kernel B: backtracking (unchanged; measured cheap).
// ---------------------------------------------------------------------------
__global__ __launch_bounds__(1024) void crf_backtrack(
    const uint8_t* __restrict__ bp,
    int* __restrict__ out)
{
    __shared__ uint8_t bpl[BP_STRIDE];     // 41944 B
    __shared__ int maps[16][NCLASS];       // chunk boundary maps
    __shared__ int entry[16];              // true tag at each chunk end

    const int b = blockIdx.x;
    const int tid = threadIdx.x;
    const int w = tid >> 6;
    const int lane = tid & 63;

    {
        const uint32_t* src = (const uint32_t*)(bp + (size_t)b * BP_STRIDE);
        uint32_t* dst = (uint32_t*)bpl;
        for (int i = tid; i < BP_STRIDE / 4; i += 1024) dst[i] = src[i];
    }
    __syncthreads();

    const int cs = w * 64;
    const int ce = min(cs + 64, TLEN - 1);  // last chunk: 63 columns
    const int L = ce - cs;

    // Phase 1: hypothesis walk for all 41 entering tags (lane = hypothesis)
    {
        int xx = (lane < NCLASS) ? lane : 0;
        for (int t = ce; t > cs; --t)
            xx = bpl[(t - 1) * NCLASS + xx];
        if (lane < NCLASS) maps[w][lane] = xx;
    }
    __syncthreads();

    // Stitch chunk boundaries serially on one thread
    if (tid == 0) {
        int cur = out[(size_t)b * TLEN + (TLEN - 1)];  // tag @ T-1 from fwd
        for (int ww = 15; ww >= 0; --ww) {
            entry[ww] = cur;
            cur = maps[ww][cur];
        }
    }
    __syncthreads();

    // Phase 2: replay with true entering tag; lane l captures step l's tag
    {
        int xx = entry[w];
        int cap = 0;
        for (int k = 0; k < L; ++k) {
            xx = bpl[(ce - 1 - k) * NCLASS + xx];
            if (k == lane) cap = xx;
        }
        if (lane < L) out[(size_t)b * TLEN + (ce - 1 - lane)] = cap;
    }
}

// ---------------------------------------------------------------------------
extern "C" void kernel_launch(void* const* d_in, const int* in_sizes, int n_in,
                              void* d_out, int out_size, void* d_ws, size_t ws_size,
                              hipStream_t stream) {
    const float* x       = (const float*)d_in[0];
    const float* start_t = (const float*)d_in[1];
    const float* end_t   = (const float*)d_in[2];
    const float* trans   = (const float*)d_in[3];
    int* out = (int*)d_out;
    uint8_t* bp = (uint8_t*)d_ws;  // needs NBATCH * BP_STRIDE = ~42.9 MB

    crf_forward<<<NBATCH, 64, 0, stream>>>(x, start_t, end_t, trans, bp, out);
    crf_backtrack<<<NBATCH, 1024, 0, stream>>>(bp, out);
}